// Round 1
// baseline (428.904 us; speedup 1.0000x reference)
//
#include <hip/hip_runtime.h>
#include <hip/hip_bf16.h>

typedef __attribute__((ext_vector_type(4))) float f32x4;
typedef __attribute__((ext_vector_type(8))) short s16x8;

#define NROWS 4096
#define DMODEL 256
#define NHEAD 8
#define HDIM 32

#define SK_STRIDE 40   // 64 keys x 32 hd tile, padded: 16B-aligned rows, 2-way banks
#define SV_STRIDE 72   // 32 hd x 64 keys tile (V transposed)
#define SP_STRIDE 40   // 16 q x 64 keys P tile per wave

__device__ __forceinline__ short bf16r(float f) {
    union { float f; unsigned u; } v; v.f = f;
    unsigned r = v.u + 0x7fffu + ((v.u >> 16) & 1u);  // RNE
    return (short)(r >> 16);
}

__device__ __forceinline__ s16x8 pack8(float4 a, float4 b) {
    s16x8 r;
    r[0] = bf16r(a.x); r[1] = bf16r(a.y); r[2] = bf16r(a.z); r[3] = bf16r(a.w);
    r[4] = bf16r(b.x); r[5] = bf16r(b.y); r[6] = bf16r(b.z); r[7] = bf16r(b.w);
    return r;
}

// ---------------------------------------------------------------------------
// adj (4096x4096 int32) -> packed bitmask (4096 x 128 u32), diag OR'd in.
// One wave per 64-column chunk; coalesced 256B reads + ballot.
__global__ __launch_bounds__(256) void pack_adj(const int* __restrict__ adj,
                                                unsigned* __restrict__ mask) {
    const int gw   = (blockIdx.x * 256 + threadIdx.x) >> 6;
    const int lane = threadIdx.x & 63;
    const int row  = gw >> 6;
    const int chunk = gw & 63;
    const int c = chunk * 64 + lane;
    int a = adj[(size_t)row * NROWS + c];
    unsigned long long m = __ballot(a > 0 || c == row);
    if (lane == 0)      mask[row * 128 + chunk * 2]     = (unsigned)m;
    else if (lane == 1) mask[row * 128 + chunk * 2 + 1] = (unsigned)(m >> 32);
}

// ---------------------------------------------------------------------------
// Generic C[n][o] = sum_k A[n][k] * W[o][k] + bias[o]  (optional relu)
// f32 in/out, bf16 MFMA inside. Block = 64x64 output tile, 4 waves, each 16x64.
__device__ __forceinline__ void gemm_tile(const float* __restrict__ A,
                                          const float* __restrict__ W,
                                          const float* __restrict__ bias,
                                          float* __restrict__ C,
                                          int K, int Ocols, int relu,
                                          int n0blk, int o0) {
    const int tid  = threadIdx.x;
    const int wv   = tid >> 6, lane = tid & 63;
    const int quad = lane >> 4, col = lane & 15;
    const int n0 = n0blk + wv * 16;
    f32x4 acc[4] = {{0,0,0,0},{0,0,0,0},{0,0,0,0},{0,0,0,0}};
    const float* arow  = A + (size_t)(n0 + col) * K + quad * 8;
    const float* wbase = W + (size_t)(o0 + col) * K + quad * 8;
    for (int k0 = 0; k0 < K; k0 += 32) {
        float4 a0 = *(const float4*)(arow + k0);
        float4 a1 = *(const float4*)(arow + k0 + 4);
        s16x8 af = pack8(a0, a1);
#pragma unroll
        for (int c = 0; c < 4; ++c) {
            const float* wr = wbase + (size_t)(c * 16) * K + k0;
            float4 b0 = *(const float4*)(wr);
            float4 b1 = *(const float4*)(wr + 4);
            s16x8 bf = pack8(b0, b1);
            acc[c] = __builtin_amdgcn_mfma_f32_16x16x32_bf16(af, bf, acc[c], 0, 0, 0);
        }
    }
#pragma unroll
    for (int c = 0; c < 4; ++c) {
        float bv = bias ? bias[o0 + c * 16 + col] : 0.f;
#pragma unroll
        for (int r = 0; r < 4; ++r) {
            float v = acc[c][r] + bv;
            if (relu) v = fmaxf(v, 0.f);
            C[(size_t)(n0 + quad * 4 + r) * Ocols + o0 + c * 16 + col] = v;
        }
    }
}

__global__ __launch_bounds__(256) void gemm_kernel(const float* __restrict__ A,
                                                   const float* __restrict__ W,
                                                   const float* __restrict__ bias,
                                                   float* __restrict__ C,
                                                   int K, int Ocols, int relu) {
    gemm_tile(A, W, bias, C, K, Ocols, relu, blockIdx.x * 64, blockIdx.y * 64);
}

// Q/K/V in one launch: blockIdx.z selects the weight/bias/output.
__global__ __launch_bounds__(256) void qkv_kernel(const float* __restrict__ X,
                                                  const float* __restrict__ Wq,
                                                  const float* __restrict__ Wk,
                                                  const float* __restrict__ Wv,
                                                  const float* __restrict__ bq,
                                                  const float* __restrict__ bk,
                                                  const float* __restrict__ bv,
                                                  float* __restrict__ QKV) {
    const float* W = (blockIdx.z == 0) ? Wq : (blockIdx.z == 1 ? Wk : Wv);
    const float* b = (blockIdx.z == 0) ? bq : (blockIdx.z == 1 ? bk : bv);
    float* C = QKV + (size_t)blockIdx.z * NROWS * DMODEL;
    gemm_tile(X, W, b, C, DMODEL, DMODEL, 0, blockIdx.x * 64, blockIdx.y * 64);
}

// ---------------------------------------------------------------------------
// Flash-style masked attention. Block = (64 queries, 1 head), 4 waves x 16 q.
// Key tiles of 64. HD=32 == MFMA K, so S-tile = 1 MFMA.
__global__ __launch_bounds__(256) void attn_kernel(const float* __restrict__ Qm,
                                                   const float* __restrict__ Km,
                                                   const float* __restrict__ Vm,
                                                   const unsigned* __restrict__ mask,
                                                   float* __restrict__ Om) {
    __shared__ short sK[64 * SK_STRIDE];
    __shared__ short sVt[32 * SV_STRIDE];
    __shared__ short sP[4][16 * SP_STRIDE];
    __shared__ unsigned sM[128];

    const int tid  = threadIdx.x;
    const int wv   = tid >> 6, lane = tid & 63;
    const int quad = lane >> 4, col = lane & 15;
    const int h  = blockIdx.y;
    const int q0 = blockIdx.x * 64;

    // Q fragment (A-operand): m = lane&15 (q row), k = quad*8 + j (hd)
    s16x8 qf;
    {
        const float* qp = Qm + (size_t)(q0 + wv * 16 + col) * DMODEL + h * HDIM + quad * 8;
        qf = pack8(*(const float4*)qp, *(const float4*)(qp + 4));
    }

    f32x4 acc0 = {0,0,0,0}, acc1 = {0,0,0,0};
    float mrow[4] = {-__builtin_inff(), -__builtin_inff(), -__builtin_inff(), -__builtin_inff()};
    float lrow[4] = {0.f, 0.f, 0.f, 0.f};
    const float scale = 0.17677669529663687f;  // 1/sqrt(32)

    const int keyrow = tid >> 2, ch = tid & 3;

    for (int kt = 0; kt < 64; ++kt) {
        __syncthreads();
        {   // stage K (row-major) and V (transposed) for this head, + mask words
            const size_t gk = (size_t)(kt * 64 + keyrow) * DMODEL + h * HDIM + ch * 8;
            const float* kp = Km + gk;
            s16x8 kb = pack8(*(const float4*)kp, *(const float4*)(kp + 4));
            *(s16x8*)&sK[keyrow * SK_STRIDE + ch * 8] = kb;
            const float* vp = Vm + gk;
            float4 v0a = *(const float4*)vp, v1a = *(const float4*)(vp + 4);
            float vv[8] = {v0a.x, v0a.y, v0a.z, v0a.w, v1a.x, v1a.y, v1a.z, v1a.w};
#pragma unroll
            for (int j = 0; j < 8; ++j)
                sVt[(ch * 8 + j) * SV_STRIDE + keyrow] = bf16r(vv[j]);
            if (tid < 128)
                sM[tid] = mask[(size_t)(q0 + (tid >> 1)) * 128 + kt * 2 + (tid & 1)];
        }
        __syncthreads();

        // S = Q K^T (4 sub-tiles of 16 cols), scale + mask
        float s[4][4];
#pragma unroll
        for (int t = 0; t < 4; ++t) {
            s16x8 kb = *(const s16x8*)&sK[(t * 16 + col) * SK_STRIDE + quad * 8];
            f32x4 z = {0,0,0,0};
            f32x4 sv = __builtin_amdgcn_mfma_f32_16x16x32_bf16(qf, kb, z, 0, 0, 0);
#pragma unroll
            for (int r = 0; r < 4; ++r) {
                int rl = wv * 16 + quad * 4 + r;
                unsigned wd = sM[rl * 2 + (t >> 1)];
                bool ok = (wd >> ((t & 1) * 16 + col)) & 1u;
                s[t][r] = ok ? sv[r] * scale : -1e9f;
            }
        }
        // online softmax: row = (quad*4+r), spread over 16 lanes (cols)
        float alpha[4], mnew[4];
#pragma unroll
        for (int r = 0; r < 4; ++r) {
            float mx = fmaxf(fmaxf(s[0][r], s[1][r]), fmaxf(s[2][r], s[3][r]));
            mx = fmaxf(mx, __shfl_xor(mx, 1, 64));
            mx = fmaxf(mx, __shfl_xor(mx, 2, 64));
            mx = fmaxf(mx, __shfl_xor(mx, 4, 64));
            mx = fmaxf(mx, __shfl_xor(mx, 8, 64));
            mnew[r] = fmaxf(mrow[r], mx);
            alpha[r] = __expf(mrow[r] - mnew[r]);
            mrow[r] = mnew[r];
        }
        float rs[4] = {0.f, 0.f, 0.f, 0.f};
#pragma unroll
        for (int t = 0; t < 4; ++t)
#pragma unroll
            for (int r = 0; r < 4; ++r) {
                float pv = __expf(s[t][r] - mnew[r]);
                rs[r] += pv;
                sP[wv][(quad * 4 + r) * SP_STRIDE + t * 16 + col] = bf16r(pv);
            }
#pragma unroll
        for (int r = 0; r < 4; ++r) {
            float v = rs[r];
            v += __shfl_xor(v, 1, 64);
            v += __shfl_xor(v, 2, 64);
            v += __shfl_xor(v, 4, 64);
            v += __shfl_xor(v, 8, 64);
            lrow[r] = lrow[r] * alpha[r] + v;
            acc0[r] *= alpha[r];
            acc1[r] *= alpha[r];
        }
        // P (C-layout) -> LDS -> A-layout; V from transposed LDS as B-operand
        s16x8 pa0  = *(const s16x8*)&sP[wv][col * SP_STRIDE + quad * 8];
        s16x8 pa1  = *(const s16x8*)&sP[wv][col * SP_STRIDE + 32 + quad * 8];
        s16x8 vb00 = *(const s16x8*)&sVt[col * SV_STRIDE + quad * 8];
        s16x8 vb01 = *(const s16x8*)&sVt[col * SV_STRIDE + 32 + quad * 8];
        s16x8 vb10 = *(const s16x8*)&sVt[(16 + col) * SV_STRIDE + quad * 8];
        s16x8 vb11 = *(const s16x8*)&sVt[(16 + col) * SV_STRIDE + 32 + quad * 8];
        acc0 = __builtin_amdgcn_mfma_f32_16x16x32_bf16(pa0, vb00, acc0, 0, 0, 0);
        acc0 = __builtin_amdgcn_mfma_f32_16x16x32_bf16(pa1, vb01, acc0, 0, 0, 0);
        acc1 = __builtin_amdgcn_mfma_f32_16x16x32_bf16(pa0, vb10, acc1, 0, 0, 0);
        acc1 = __builtin_amdgcn_mfma_f32_16x16x32_bf16(pa1, vb11, acc1, 0, 0, 0);
    }

#pragma unroll
    for (int r = 0; r < 4; ++r) {
        float inv = 1.f / lrow[r];  // > 0: diagonal always allowed
        size_t n = q0 + wv * 16 + quad * 4 + r;
        Om[n * DMODEL + h * HDIM + col]      = acc0[r] * inv;
        Om[n * DMODEL + h * HDIM + 16 + col] = acc1[r] * inv;
    }
}

// ---------------------------------------------------------------------------
// y = LN(a + b) * g + beta, one wave per row (4 f32 per lane).
__global__ __launch_bounds__(256) void ln_kernel(const float* __restrict__ Xa,
                                                 const float* __restrict__ Xb,
                                                 const float* __restrict__ g,
                                                 const float* __restrict__ be,
                                                 float* __restrict__ Y) {
    const int wv = threadIdx.x >> 6, lane = threadIdx.x & 63;
    const int row = blockIdx.x * 4 + wv;
    const float4 av = *(const float4*)(Xa + (size_t)row * DMODEL + lane * 4);
    const float4 bv = *(const float4*)(Xb + (size_t)row * DMODEL + lane * 4);
    float v0 = av.x + bv.x, v1 = av.y + bv.y, v2 = av.z + bv.z, v3 = av.w + bv.w;
    float s = v0 + v1 + v2 + v3;
#pragma unroll
    for (int m = 1; m < 64; m <<= 1) s += __shfl_xor(s, m, 64);
    float mean = s * (1.f / 256.f);
    float d0 = v0 - mean, d1 = v1 - mean, d2 = v2 - mean, d3 = v3 - mean;
    float q = d0 * d0 + d1 * d1 + d2 * d2 + d3 * d3;
#pragma unroll
    for (int m = 1; m < 64; m <<= 1) q += __shfl_xor(q, m, 64);
    float rstd = rsqrtf(q * (1.f / 256.f) + 1e-5f);
    const float4 gv  = *(const float4*)(g + lane * 4);
    const float4 bev = *(const float4*)(be + lane * 4);
    float4 y;
    y.x = d0 * rstd * gv.x + bev.x;
    y.y = d1 * rstd * gv.y + bev.y;
    y.z = d2 * rstd * gv.z + bev.z;
    y.w = d3 * rstd * gv.w + bev.w;
    *(float4*)(Y + (size_t)row * DMODEL + lane * 4) = y;
}

// ---------------------------------------------------------------------------
extern "C" void kernel_launch(void* const* d_in, const int* in_sizes, int n_in,
                              void* d_out, int out_size, void* d_ws, size_t ws_size,
                              hipStream_t stream) {
    const float* x   = (const float*)d_in[0];
    const int*   adj = (const int*)d_in[1];
    const float* Wq  = (const float*)d_in[2];
    const float* Wk  = (const float*)d_in[3];
    const float* Wv  = (const float*)d_in[4];
    const float* bq  = (const float*)d_in[5];
    const float* bk  = (const float*)d_in[6];
    const float* bv  = (const float*)d_in[7];
    const float* Wo  = (const float*)d_in[8];
    const float* bo  = (const float*)d_in[9];
    const float* g1  = (const float*)d_in[10];
    const float* be1 = (const float*)d_in[11];
    const float* W1  = (const float*)d_in[12];
    const float* b1  = (const float*)d_in[13];
    const float* W2  = (const float*)d_in[14];
    const float* b2  = (const float*)d_in[15];
    const float* g2  = (const float*)d_in[16];
    const float* be2 = (const float*)d_in[17];
    float* out = (float*)d_out;

    const size_t NM = (size_t)NROWS * DMODEL;
    char* p = (char*)d_ws;
    unsigned* mask = (unsigned*)p;  p += (size_t)NROWS * 128 * 4;   //  2 MB
    float* qkv  = (float*)p;        p += 3 * NM * 4;                 // 12 MB
    float* obuf = (float*)p;        p += NM * 4;                     //  4 MB
    float* y1   = (float*)p;        p += NM * 4;                     //  4 MB
    float* rbuf = (float*)p;        p += (size_t)NROWS * 512 * 4;    //  8 MB
    float* hbuf = qkv;              // alias: q dead after attention
    float* t2   = qkv + NM;         // alias: k dead after attention

    pack_adj<<<dim3(NROWS * 64 / 4), dim3(256), 0, stream>>>(adj, mask);
    qkv_kernel<<<dim3(64, 4, 3), dim3(256), 0, stream>>>(x, Wq, Wk, Wv, bq, bk, bv, qkv);
    attn_kernel<<<dim3(64, NHEAD), dim3(256), 0, stream>>>(qkv, qkv + NM, qkv + 2 * NM, mask, obuf);
    gemm_kernel<<<dim3(64, 4), dim3(256), 0, stream>>>(obuf, Wo, bo, hbuf, 256, 256, 0);
    ln_kernel<<<dim3(1024), dim3(256), 0, stream>>>(x, hbuf, g1, be1, y1);
    gemm_kernel<<<dim3(64, 8), dim3(256), 0, stream>>>(y1, W1, b1, rbuf, 256, 512, 1);
    gemm_kernel<<<dim3(64, 4), dim3(256), 0, stream>>>(rbuf, W2, b2, t2, 512, 256, 0);
    ln_kernel<<<dim3(1024), dim3(256), 0, stream>>>(y1, t2, g2, be2, out);
}

// Round 2
// 316.892 us; speedup vs baseline: 1.3535x; 1.3535x over previous
//
#include <hip/hip_runtime.h>
#include <hip/hip_bf16.h>

typedef __attribute__((ext_vector_type(4))) float f32x4;
typedef __attribute__((ext_vector_type(8))) short s16x8;
typedef __attribute__((ext_vector_type(4))) short s16x4;

#define NROWS 4096
#define DMODEL 256
#define NHEAD 8
#define HDIM 32
#define PSTRIDE 72   // halfwords per q-row of P scratch: 144 B rows, 16B-aligned

__device__ __forceinline__ short bf16r(float f) {
    union { float f; unsigned u; } v; v.f = f;
    unsigned r = v.u + 0x7fffu + ((v.u >> 16) & 1u);  // RNE
    return (short)(r >> 16);
}

__device__ __forceinline__ s16x8 pack8(float4 a, float4 b) {
    s16x8 r;
    r[0] = bf16r(a.x); r[1] = bf16r(a.y); r[2] = bf16r(a.z); r[3] = bf16r(a.w);
    r[4] = bf16r(b.x); r[5] = bf16r(b.y); r[6] = bf16r(b.z); r[7] = bf16r(b.w);
    return r;
}

// ---------------------------------------------------------------------------
// adj (4096x4096 int32) -> packed bitmask (4096 x 128 u32), diag OR'd in.
__global__ __launch_bounds__(256) void pack_adj(const int* __restrict__ adj,
                                                unsigned* __restrict__ mask) {
    const int gw   = (blockIdx.x * 256 + threadIdx.x) >> 6;
    const int lane = threadIdx.x & 63;
    const int row  = gw >> 6;
    const int chunk = gw & 63;
    const int c = chunk * 64 + lane;
    int a = adj[(size_t)row * NROWS + c];
    unsigned long long m = __ballot(a > 0 || c == row);
    if (lane == 0)      mask[row * 128 + chunk * 2]     = (unsigned)m;
    else if (lane == 1) mask[row * 128 + chunk * 2 + 1] = (unsigned)(m >> 32);
}

// ---------------------------------------------------------------------------
// Convert all 6 weight matrices to bf16 once (concatenated: Wq,Wk,Wv,Wo,W1,W2)
__global__ __launch_bounds__(256) void prep_w(const float* __restrict__ Wq,
                                              const float* __restrict__ Wk,
                                              const float* __restrict__ Wv,
                                              const float* __restrict__ Wo,
                                              const float* __restrict__ W1,
                                              const float* __restrict__ W2,
                                              short* __restrict__ out) {
    int i = (blockIdx.x * 256 + threadIdx.x) * 8;  // total 524288 floats
    const float* src; int off;
    if (i < 262144) {
        const float* ws[4] = {Wq, Wk, Wv, Wo};
        src = ws[i >> 16]; off = i & 65535;
    } else if (i < 393216) { src = W1; off = i - 262144; }
    else                   { src = W2; off = i - 393216; }
    float4 a = *(const float4*)(src + off);
    float4 b = *(const float4*)(src + off + 4);
    *(s16x8*)(out + i) = pack8(a, b);
}

// ---------------------------------------------------------------------------
// QKV projection: A = x (f32), W = bf16. Outputs bf16 in attention-ready
// layouts: Qb[n][d], Kb[h][key][hd], Vtb[h][hd][key].
__global__ __launch_bounds__(256) void qkv_kernel(const float* __restrict__ X,
                                                  const short* __restrict__ Wb,
                                                  const float* __restrict__ bq,
                                                  const float* __restrict__ bk,
                                                  const float* __restrict__ bv,
                                                  short* __restrict__ Qb,
                                                  short* __restrict__ Kb,
                                                  short* __restrict__ Vtb) {
    const int z = blockIdx.z;
    const short* W = Wb + (size_t)z * 65536;
    const float* bias = (z == 0) ? bq : (z == 1 ? bk : bv);
    const int tid = threadIdx.x;
    const int wv = tid >> 6, lane = tid & 63;
    const int quad = lane >> 4, col = lane & 15;
    const int n0 = blockIdx.x * 64 + wv * 16;
    const int o0 = blockIdx.y * 64;

    f32x4 zero = {0.f, 0.f, 0.f, 0.f};
    f32x4 acc[4] = {zero, zero, zero, zero};
    const float* ap = X + (size_t)(n0 + col) * DMODEL + quad * 8;
    const short* wp = W + (size_t)(o0 + col) * DMODEL + quad * 8;
    for (int k0 = 0; k0 < DMODEL; k0 += 32) {
        float4 a0 = *(const float4*)(ap + k0);
        float4 a1 = *(const float4*)(ap + k0 + 4);
        s16x8 af = pack8(a0, a1);
#pragma unroll
        for (int c = 0; c < 4; ++c) {
            s16x8 bf = *(const s16x8*)(wp + (size_t)c * 16 * DMODEL + k0);
            acc[c] = __builtin_amdgcn_mfma_f32_16x16x32_bf16(af, bf, acc[c], 0, 0, 0);
        }
    }
#pragma unroll
    for (int c = 0; c < 4; ++c) {
        int o = o0 + c * 16 + col;
        float bvv = bias[o];
#pragma unroll
        for (int r = 0; r < 4; ++r) {
            int n = n0 + quad * 4 + r;
            short b = bf16r(acc[c][r] + bvv);
            if (z == 0)      Qb[(size_t)n * DMODEL + o] = b;
            else if (z == 1) Kb[(size_t)(o >> 5) * NROWS * HDIM + (size_t)n * HDIM + (o & 31)] = b;
            else             Vtb[(size_t)o * NROWS + n] = b;
        }
    }
}

// ---------------------------------------------------------------------------
// Flash attention, S^T orientation, key-split across 4 waves, no K-loop LDS.
// Block = (16 q, 1 head); wave w owns keys [w*1024, w*1024+1024).
__global__ __launch_bounds__(256) void attn_kernel(const short* __restrict__ Qb,
                                                   const short* __restrict__ Kb,
                                                   const short* __restrict__ Vtb,
                                                   const unsigned* __restrict__ mask,
                                                   short* __restrict__ Om) {
    __shared__ short sP[4][16 * PSTRIDE];
    __shared__ float sO[4][32][16];
    __shared__ float sml[4][2][16];

    const int tid = threadIdx.x;
    const int wv = tid >> 6, lane = tid & 63;
    const int quad = lane >> 4, col = lane & 15;
    const int h = blockIdx.x & 7;
    const int q0 = (blockIdx.x >> 3) << 4;
    const int kw = wv * 1024;

    // Q as B-operand: B[n=col=q][k=quad*8+j=hd]
    s16x8 qf = *(const s16x8*)(Qb + (size_t)(q0 + col) * DMODEL + h * HDIM + quad * 8);

    const short* kp = Kb + (size_t)h * NROWS * HDIM + (size_t)(kw + col) * HDIM + quad * 8;
    const short* vp0 = Vtb + (size_t)(h * HDIM + col) * NROWS + kw + quad * 8;
    const short* vp1 = vp0 + (size_t)16 * NROWS;
    const unsigned* mp = mask + (size_t)(q0 + col) * 128 + (kw >> 5);
    short* pbase = &sP[wv][0];

    f32x4 acc0 = {0.f, 0.f, 0.f, 0.f}, acc1 = {0.f, 0.f, 0.f, 0.f};
    float m2 = -__builtin_inff(), l = 0.f;
    const float SC2  = 0.17677669529663687f * 1.4426950408889634f;  // scale*log2e
    const float NEG2 = -1.4426950408889634e9f;                      // -1e9*log2e

    for (int it = 0; it < 16; ++it) {
        s16x8 kf0 = *(const s16x8*)(kp);
        s16x8 kf1 = *(const s16x8*)(kp + 16 * HDIM);
        s16x8 kf2 = *(const s16x8*)(kp + 32 * HDIM);
        s16x8 kf3 = *(const s16x8*)(kp + 48 * HDIM);
        s16x8 vf00 = *(const s16x8*)(vp0);
        s16x8 vf01 = *(const s16x8*)(vp0 + 32);
        s16x8 vf10 = *(const s16x8*)(vp1);
        s16x8 vf11 = *(const s16x8*)(vp1 + 32);
        unsigned w0 = mp[0], w1 = mp[1];
        kp += 64 * HDIM; vp0 += 64; vp1 += 64; mp += 2;

        f32x4 z = {0.f, 0.f, 0.f, 0.f};
        // S^T tiles: D[m=key][n=q]; A=K frag, B=Q frag
        f32x4 st[4];
        st[0] = __builtin_amdgcn_mfma_f32_16x16x32_bf16(kf0, qf, z, 0, 0, 0);
        st[1] = __builtin_amdgcn_mfma_f32_16x16x32_bf16(kf1, qf, z, 0, 0, 0);
        st[2] = __builtin_amdgcn_mfma_f32_16x16x32_bf16(kf2, qf, z, 0, 0, 0);
        st[3] = __builtin_amdgcn_mfma_f32_16x16x32_bf16(kf3, qf, z, 0, 0, 0);

        float sc[4][4];
#pragma unroll
        for (int t = 0; t < 4; ++t) {
            unsigned w = (t < 2) ? w0 : w1;
#pragma unroll
            for (int r = 0; r < 4; ++r) {
                int bit = (t & 1) * 16 + quad * 4 + r;
                bool ok = (w >> bit) & 1u;
                sc[t][r] = ok ? st[t][r] * SC2 : NEG2;
            }
        }
        float mx = sc[0][0];
#pragma unroll
        for (int t = 0; t < 4; ++t)
#pragma unroll
            for (int r = 0; r < 4; ++r) mx = fmaxf(mx, sc[t][r]);
        mx = fmaxf(mx, __shfl_xor(mx, 16, 64));
        mx = fmaxf(mx, __shfl_xor(mx, 32, 64));
        float mn = fmaxf(m2, mx);
        float alpha = exp2f(m2 - mn);   // m2=-inf, mn finite -> 0 (mn >= NEG2 always)
        m2 = mn;

        float p[4][4];
        float rs = 0.f;
#pragma unroll
        for (int t = 0; t < 4; ++t)
#pragma unroll
            for (int r = 0; r < 4; ++r) { p[t][r] = exp2f(sc[t][r] - mn); rs += p[t][r]; }
        rs += __shfl_xor(rs, 16, 64);
        rs += __shfl_xor(rs, 32, 64);
        l = l * alpha + rs;
#pragma unroll
        for (int r = 0; r < 4; ++r) { acc0[r] *= alpha; acc1[r] *= alpha; }

        // P[q][key] to per-wave LDS scratch (same-wave producer/consumer, no barrier)
#pragma unroll
        for (int t = 0; t < 4; ++t) {
            s16x4 pt;
            pt[0] = bf16r(p[t][0]); pt[1] = bf16r(p[t][1]);
            pt[2] = bf16r(p[t][2]); pt[3] = bf16r(p[t][3]);
            *(s16x4*)(pbase + col * PSTRIDE + t * 16 + quad * 4) = pt;
        }
        s16x8 pb0 = *(const s16x8*)(pbase + col * PSTRIDE + quad * 8);
        s16x8 pb1 = *(const s16x8*)(pbase + col * PSTRIDE + 32 + quad * 8);

        // O^T[hd][q] += V^T frag (A) x P frag (B)
        acc0 = __builtin_amdgcn_mfma_f32_16x16x32_bf16(vf00, pb0, acc0, 0, 0, 0);
        acc0 = __builtin_amdgcn_mfma_f32_16x16x32_bf16(vf01, pb1, acc0, 0, 0, 0);
        acc1 = __builtin_amdgcn_mfma_f32_16x16x32_bf16(vf10, pb0, acc1, 0, 0, 0);
        acc1 = __builtin_amdgcn_mfma_f32_16x16x32_bf16(vf11, pb1, acc1, 0, 0, 0);
    }

    // merge the 4 key-partitions
    if (quad == 0) { sml[wv][0][col] = m2; sml[wv][1][col] = l; }
#pragma unroll
    for (int r = 0; r < 4; ++r) {
        sO[wv][quad * 4 + r][col]      = acc0[r];
        sO[wv][16 + quad * 4 + r][col] = acc1[r];
    }
    __syncthreads();

    const int q = tid >> 4, d = tid & 15;
    float m0 = sml[0][0][q], m1 = sml[1][0][q], ma = sml[2][0][q], mb = sml[3][0][q];
    float ms = fmaxf(fmaxf(m0, m1), fmaxf(ma, mb));
    float f0 = exp2f(m0 - ms), f1 = exp2f(m1 - ms), f2 = exp2f(ma - ms), f3 = exp2f(mb - ms);
    float ls = f0 * sml[0][1][q] + f1 * sml[1][1][q] + f2 * sml[2][1][q] + f3 * sml[3][1][q];
    float inv = 1.f / ls;  // diag always allowed -> ls > 0
    float v0 = f0 * sO[0][d][q] + f1 * sO[1][d][q] + f2 * sO[2][d][q] + f3 * sO[3][d][q];
    float v1 = f0 * sO[0][16 + d][q] + f1 * sO[1][16 + d][q] + f2 * sO[2][16 + d][q] + f3 * sO[3][16 + d][q];
    Om[(size_t)(q0 + q) * DMODEL + h * HDIM + d]      = bf16r(v0 * inv);
    Om[(size_t)(q0 + q) * DMODEL + h * HDIM + 16 + d] = bf16r(v1 * inv);
}

// ---------------------------------------------------------------------------
// bf16-in GEMM: C = A(bf16) * W(bf16)^T + bias.  Cb!=null -> bf16 out (+relu),
// else f32 out.
__global__ __launch_bounds__(256) void gemm_b16(const short* __restrict__ A,
                                                const short* __restrict__ W,
                                                const float* __restrict__ bias,
                                                float* __restrict__ Cf,
                                                short* __restrict__ Cb,
                                                int K, int Ocols, int relu) {
    const int tid = threadIdx.x;
    const int wv = tid >> 6, lane = tid & 63;
    const int quad = lane >> 4, col = lane & 15;
    const int n0 = blockIdx.x * 64 + wv * 16;
    const int o0 = blockIdx.y * 64;
    f32x4 zero = {0.f, 0.f, 0.f, 0.f};
    f32x4 acc[4] = {zero, zero, zero, zero};
    const short* ap = A + (size_t)(n0 + col) * K + quad * 8;
    const short* wp = W + (size_t)(o0 + col) * K + quad * 8;
    for (int k0 = 0; k0 < K; k0 += 32) {
        s16x8 af = *(const s16x8*)(ap + k0);
#pragma unroll
        for (int c = 0; c < 4; ++c) {
            s16x8 bf = *(const s16x8*)(wp + (size_t)c * 16 * K + k0);
            acc[c] = __builtin_amdgcn_mfma_f32_16x16x32_bf16(af, bf, acc[c], 0, 0, 0);
        }
    }
#pragma unroll
    for (int c = 0; c < 4; ++c) {
        int o = o0 + c * 16 + col;
        float bvv = bias[o];
#pragma unroll
        for (int r = 0; r < 4; ++r) {
            int n = n0 + quad * 4 + r;
            float v = acc[c][r] + bvv;
            if (relu) v = fmaxf(v, 0.f);
            if (Cb) Cb[(size_t)n * Ocols + o] = bf16r(v);
            else    Cf[(size_t)n * Ocols + o] = v;
        }
    }
}

// ---------------------------------------------------------------------------
// y = LN(a+b)*g + beta; writes f32 Y and optional bf16 Yb.
__global__ __launch_bounds__(256) void ln_kernel(const float* __restrict__ Xa,
                                                 const float* __restrict__ Xb,
                                                 const float* __restrict__ g,
                                                 const float* __restrict__ be,
                                                 float* __restrict__ Y,
                                                 short* __restrict__ Yb) {
    const int wv = threadIdx.x >> 6, lane = threadIdx.x & 63;
    const int row = blockIdx.x * 4 + wv;
    const float4 av = *(const float4*)(Xa + (size_t)row * DMODEL + lane * 4);
    const float4 bv = *(const float4*)(Xb + (size_t)row * DMODEL + lane * 4);
    float v0 = av.x + bv.x, v1 = av.y + bv.y, v2 = av.z + bv.z, v3 = av.w + bv.w;
    float s = v0 + v1 + v2 + v3;
#pragma unroll
    for (int m = 1; m < 64; m <<= 1) s += __shfl_xor(s, m, 64);
    float mean = s * (1.f / 256.f);
    float d0 = v0 - mean, d1 = v1 - mean, d2 = v2 - mean, d3 = v3 - mean;
    float q = d0 * d0 + d1 * d1 + d2 * d2 + d3 * d3;
#pragma unroll
    for (int m = 1; m < 64; m <<= 1) q += __shfl_xor(q, m, 64);
    float rstd = rsqrtf(q * (1.f / 256.f) + 1e-5f);
    const float4 gv  = *(const float4*)(g + lane * 4);
    const float4 bev = *(const float4*)(be + lane * 4);
    float4 y;
    y.x = d0 * rstd * gv.x + bev.x;
    y.y = d1 * rstd * gv.y + bev.y;
    y.z = d2 * rstd * gv.z + bev.z;
    y.w = d3 * rstd * gv.w + bev.w;
    *(float4*)(Y + (size_t)row * DMODEL + lane * 4) = y;
    if (Yb) {
        s16x4 yb;
        yb[0] = bf16r(y.x); yb[1] = bf16r(y.y); yb[2] = bf16r(y.z); yb[3] = bf16r(y.w);
        *(s16x4*)(Yb + (size_t)row * DMODEL + lane * 4) = yb;
    }
}

// ---------------------------------------------------------------------------
extern "C" void kernel_launch(void* const* d_in, const int* in_sizes, int n_in,
                              void* d_out, int out_size, void* d_ws, size_t ws_size,
                              hipStream_t stream) {
    const float* x   = (const float*)d_in[0];
    const int*   adj = (const int*)d_in[1];
    const float* Wq  = (const float*)d_in[2];
    const float* Wk  = (const float*)d_in[3];
    const float* Wv  = (const float*)d_in[4];
    const float* bq  = (const float*)d_in[5];
    const float* bk  = (const float*)d_in[6];
    const float* bv  = (const float*)d_in[7];
    const float* Wo  = (const float*)d_in[8];
    const float* bo  = (const float*)d_in[9];
    const float* g1  = (const float*)d_in[10];
    const float* be1 = (const float*)d_in[11];
    const float* W1  = (const float*)d_in[12];
    const float* b1  = (const float*)d_in[13];
    const float* W2  = (const float*)d_in[14];
    const float* b2  = (const float*)d_in[15];
    const float* g2  = (const float*)d_in[16];
    const float* be2 = (const float*)d_in[17];
    float* out = (float*)d_out;

    const size_t NM = (size_t)NROWS * DMODEL;
    char* p = (char*)d_ws;
    unsigned* mask = (unsigned*)p; p += (size_t)NROWS * 128 * 4;  // 2 MB
    short* Wb   = (short*)p;       p += (size_t)524288 * 2;       // 1 MB
    short* Qb   = (short*)p;       p += NM * 2;                   // 2 MB
    short* Kb   = (short*)p;       p += NM * 2;                   // 2 MB
    short* Vtb  = (short*)p;       p += NM * 2;                   // 2 MB
    short* Omb  = (short*)p;       p += NM * 2;                   // 2 MB
    float* hbuf = (float*)p;       p += NM * 4;                   // 4 MB
    float* y1   = (float*)p;       p += NM * 4;                   // 4 MB
    short* y1b  = (short*)p;       p += NM * 2;                   // 2 MB
    short* rbuf = (short*)p;       p += (size_t)NROWS * 512 * 2;  // 4 MB
    float* t2   = (float*)p;       p += NM * 4;                   // 4 MB

    pack_adj<<<dim3(NROWS * 64 / 4), dim3(256), 0, stream>>>(adj, mask);
    prep_w<<<dim3(256), dim3(256), 0, stream>>>(Wq, Wk, Wv, Wo, W1, W2, Wb);
    qkv_kernel<<<dim3(64, 4, 3), dim3(256), 0, stream>>>(x, Wb, bq, bk, bv, Qb, Kb, Vtb);
    attn_kernel<<<dim3(2048), dim3(256), 0, stream>>>(Qb, Kb, Vtb, mask, Omb);
    gemm_b16<<<dim3(64, 4), dim3(256), 0, stream>>>(Omb, Wb + 196608, bo, hbuf, nullptr, 256, 256, 0);
    ln_kernel<<<dim3(1024), dim3(256), 0, stream>>>(x, hbuf, g1, be1, y1, y1b);
    gemm_b16<<<dim3(64, 8), dim3(256), 0, stream>>>(y1b, Wb + 262144, b1, nullptr, rbuf, 256, 512, 1);
    gemm_b16<<<dim3(64, 4), dim3(256), 0, stream>>>(rbuf, Wb + 393216, b2, t2, nullptr, 512, 256, 0);
    ln_kernel<<<dim3(1024), dim3(256), 0, stream>>>(y1, t2, g2, be2, out, nullptr);
}

// Round 3
// 265.972 us; speedup vs baseline: 1.6126x; 1.1914x over previous
//
#include <hip/hip_runtime.h>
#include <hip/hip_bf16.h>

typedef __attribute__((ext_vector_type(4))) float f32x4;
typedef __attribute__((ext_vector_type(8))) short s16x8;
typedef __attribute__((ext_vector_type(4))) short s16x4;

#define NROWS 4096
#define DMODEL 256
#define NHEAD 8
#define HDIM 32
#define PSTRIDE 72     // halfwords per P-scratch row: 144 B, 16B-aligned
#define OSTRIDE 36     // f32 per sO row: quad stride 144B -> 2-way banks (free)
#define M2C 24.0f      // fixed softmax max (log2 domain); scores |st|<~8

__device__ __forceinline__ short bf16r(float f) {
    union { float f; unsigned u; } v; v.f = f;
    unsigned r = v.u + 0x7fffu + ((v.u >> 16) & 1u);  // RNE
    return (short)(r >> 16);
}

__device__ __forceinline__ float fexp2(float x) {
#if __has_builtin(__builtin_amdgcn_exp2f)
    return __builtin_amdgcn_exp2f(x);
#else
    return exp2f(x);
#endif
}

__device__ __forceinline__ unsigned pk_bf16(float a, float b) {
#if __has_builtin(__builtin_amdgcn_cvt_pk_bf16_f32)
    typedef __bf16 bf2 __attribute__((ext_vector_type(2)));
    union { bf2 h; unsigned u; } c;
    c.h = __builtin_amdgcn_cvt_pk_bf16_f32(a, b);
    return c.u;
#else
    return (unsigned)(unsigned short)bf16r(a) | ((unsigned)(unsigned short)bf16r(b) << 16);
#endif
}

__device__ __forceinline__ s16x8 pack8(float4 a, float4 b) {
    s16x8 r;
    r[0] = bf16r(a.x); r[1] = bf16r(a.y); r[2] = bf16r(a.z); r[3] = bf16r(a.w);
    r[4] = bf16r(b.x); r[5] = bf16r(b.y); r[6] = bf16r(b.z); r[7] = bf16r(b.w);
    return r;
}

// ---------------------------------------------------------------------------
// adj (4096x4096 int32) -> packed bitmask (4096 x 128 u32), diag OR'd in.
__global__ __launch_bounds__(256) void pack_adj(const int* __restrict__ adj,
                                                unsigned* __restrict__ mask) {
    const int gw   = (blockIdx.x * 256 + threadIdx.x) >> 6;
    const int lane = threadIdx.x & 63;
    const int row  = gw >> 6;
    const int chunk = gw & 63;
    const int c = chunk * 64 + lane;
    int a = adj[(size_t)row * NROWS + c];
    unsigned long long m = __ballot(a > 0 || c == row);
    if (lane == 0)      mask[row * 128 + chunk * 2]     = (unsigned)m;
    else if (lane == 1) mask[row * 128 + chunk * 2 + 1] = (unsigned)(m >> 32);
}

// ---------------------------------------------------------------------------
// Convert all 6 weight matrices to bf16 once (concatenated: Wq,Wk,Wv,Wo,W1,W2)
__global__ __launch_bounds__(256) void prep_w(const float* __restrict__ Wq,
                                              const float* __restrict__ Wk,
                                              const float* __restrict__ Wv,
                                              const float* __restrict__ Wo,
                                              const float* __restrict__ W1,
                                              const float* __restrict__ W2,
                                              short* __restrict__ out) {
    int i = (blockIdx.x * 256 + threadIdx.x) * 8;  // total 524288 floats
    const float* src; int off;
    if (i < 262144) {
        const float* ws[4] = {Wq, Wk, Wv, Wo};
        src = ws[i >> 16]; off = i & 65535;
    } else if (i < 393216) { src = W1; off = i - 262144; }
    else                   { src = W2; off = i - 393216; }
    float4 a = *(const float4*)(src + off);
    float4 b = *(const float4*)(src + off + 4);
    *(s16x8*)(out + i) = pack8(a, b);
}

// ---------------------------------------------------------------------------
// QKV projection. Q gets scale*log2e folded in (only attention consumes Q).
// Layouts: Qb[n][d], Kb[h][key][hd], Vtb[h][hd][key].
__global__ __launch_bounds__(256) void qkv_kernel(const float* __restrict__ X,
                                                  const short* __restrict__ Wb,
                                                  const float* __restrict__ bq,
                                                  const float* __restrict__ bk,
                                                  const float* __restrict__ bv,
                                                  short* __restrict__ Qb,
                                                  short* __restrict__ Kb,
                                                  short* __restrict__ Vtb) {
    const int z = blockIdx.z;
    const short* W = Wb + (size_t)z * 65536;
    const float* bias = (z == 0) ? bq : (z == 1 ? bk : bv);
    const int tid = threadIdx.x;
    const int wv = tid >> 6, lane = tid & 63;
    const int quad = lane >> 4, col = lane & 15;
    const int n0 = blockIdx.x * 64 + wv * 16;
    const int o0 = blockIdx.y * 64;
    const float QSC = 0.25505653437397888f;  // log2e / sqrt(32)

    f32x4 zero = {0.f, 0.f, 0.f, 0.f};
    f32x4 acc[4] = {zero, zero, zero, zero};
    const float* ap = X + (size_t)(n0 + col) * DMODEL + quad * 8;
    const short* wp = W + (size_t)(o0 + col) * DMODEL + quad * 8;
#pragma unroll
    for (int k0 = 0; k0 < DMODEL; k0 += 32) {
        float4 a0 = *(const float4*)(ap + k0);
        float4 a1 = *(const float4*)(ap + k0 + 4);
        s16x8 af = pack8(a0, a1);
#pragma unroll
        for (int c = 0; c < 4; ++c) {
            s16x8 bf = *(const s16x8*)(wp + (size_t)c * 16 * DMODEL + k0);
            acc[c] = __builtin_amdgcn_mfma_f32_16x16x32_bf16(af, bf, acc[c], 0, 0, 0);
        }
    }
#pragma unroll
    for (int c = 0; c < 4; ++c) {
        int o = o0 + c * 16 + col;
        float bvv = bias[o];
#pragma unroll
        for (int r = 0; r < 4; ++r) {
            int n = n0 + quad * 4 + r;
            float v = acc[c][r] + bvv;
            if (z == 0)      Qb[(size_t)n * DMODEL + o] = bf16r(v * QSC);
            else if (z == 1) Kb[(size_t)(o >> 5) * NROWS * HDIM + (size_t)n * HDIM + (o & 31)] = bf16r(v);
            else             Vtb[(size_t)o * NROWS + n] = bf16r(v);
        }
    }
}

// ---------------------------------------------------------------------------
// Flash attention, S^T orientation, fixed-M softmax (no running max).
// Block = (32 q, 1 head), 4 waves; wave w owns keys [w*1024, w*1024+1024).
// Each wave handles 2 q-subtiles of 16 sharing K/V fragment loads.
__global__ __launch_bounds__(256) void attn_kernel(const short* __restrict__ Qb,
                                                   const short* __restrict__ Kb,
                                                   const short* __restrict__ Vtb,
                                                   const unsigned* __restrict__ mask,
                                                   short* __restrict__ Om) {
    __shared__ short sP[4][2][16 * PSTRIDE];   // 18432 B
    __shared__ float sO[4][32][OSTRIDE];       // 18432 B
    __shared__ float sl[4][32];                //   512 B

    const int tid = threadIdx.x;
    const int wv = tid >> 6, lane = tid & 63;
    const int quad = lane >> 4, col = lane & 15;
    const int h = blockIdx.x & 7;
    const int q0 = (blockIdx.x >> 3) * 32;
    const int kw = wv * 1024;

    // Q as B-operand: B[k=quad*8+j=hd][n=col=q]
    s16x8 qf[2];
    qf[0] = *(const s16x8*)(Qb + (size_t)(q0 + col) * DMODEL + h * HDIM + quad * 8);
    qf[1] = *(const s16x8*)(Qb + (size_t)(q0 + 16 + col) * DMODEL + h * HDIM + quad * 8);

    const short* kp  = Kb + (size_t)h * NROWS * HDIM + (size_t)(kw + col) * HDIM + quad * 8;
    const short* vp0 = Vtb + (size_t)(h * HDIM + col) * NROWS + kw + quad * 8;
    const short* vp1 = vp0 + (size_t)16 * NROWS;
    const unsigned* mp0 = mask + (size_t)(q0 + col) * 128 + (kw >> 5);
    const unsigned* mp1 = mp0 + 16 * 128;

    f32x4 zero = {0.f, 0.f, 0.f, 0.f};
    f32x4 acc[2][2] = {{zero, zero}, {zero, zero}};  // [qsub][hd half]
    float rs[2] = {0.f, 0.f};
    const f32x4 cinit = {-M2C, -M2C, -M2C, -M2C};

    for (int it = 0; it < 16; ++it) {
        s16x8 kf0 = *(const s16x8*)(kp);
        s16x8 kf1 = *(const s16x8*)(kp + 16 * HDIM);
        s16x8 kf2 = *(const s16x8*)(kp + 32 * HDIM);
        s16x8 kf3 = *(const s16x8*)(kp + 48 * HDIM);
        s16x8 vf00 = *(const s16x8*)(vp0);
        s16x8 vf01 = *(const s16x8*)(vp0 + 32);
        s16x8 vf10 = *(const s16x8*)(vp1);
        s16x8 vf11 = *(const s16x8*)(vp1 + 32);
        uint2 w0 = *(const uint2*)mp0;   // qsub0: keys 0-31, 32-63
        uint2 w1 = *(const uint2*)mp1;   // qsub1
        kp += 64 * HDIM; vp0 += 64; vp1 += 64; mp0 += 2; mp1 += 2;

#pragma unroll
        for (int qs = 0; qs < 2; ++qs) {
            unsigned wlo = ((qs ? w1.x : w0.x) >> (quad * 4));
            unsigned whi = ((qs ? w1.y : w0.y) >> (quad * 4));
            // S^T tiles with C = -M2 preloaded
            f32x4 st[4];
            st[0] = __builtin_amdgcn_mfma_f32_16x16x32_bf16(kf0, qf[qs], cinit, 0, 0, 0);
            st[1] = __builtin_amdgcn_mfma_f32_16x16x32_bf16(kf1, qf[qs], cinit, 0, 0, 0);
            st[2] = __builtin_amdgcn_mfma_f32_16x16x32_bf16(kf2, qf[qs], cinit, 0, 0, 0);
            st[3] = __builtin_amdgcn_mfma_f32_16x16x32_bf16(kf3, qf[qs], cinit, 0, 0, 0);

            float p[4][4];
            float r0 = 0.f;
#pragma unroll
            for (int t = 0; t < 4; ++t) {
                unsigned w = (t < 2) ? wlo : whi;
#pragma unroll
                for (int r = 0; r < 4; ++r) {
                    float e = fexp2(st[t][r]);
                    bool ok = (w & (1u << ((t & 1) * 16 + r))) != 0u;
                    p[t][r] = ok ? e : 0.f;
                    r0 += p[t][r];
                }
            }
            rs[qs] += r0;

            // P (C-layout) -> per-wave LDS scratch -> A..B-layout (same-wave, no barrier)
            short* pb = &sP[wv][qs][0];
#pragma unroll
            for (int t = 0; t < 4; ++t) {
                uint2 pr;
                pr.x = pk_bf16(p[t][0], p[t][1]);
                pr.y = pk_bf16(p[t][2], p[t][3]);
                *(uint2*)(pb + col * PSTRIDE + t * 16 + quad * 4) = pr;
            }
            s16x8 pb0 = *(const s16x8*)(pb + col * PSTRIDE + quad * 8);
            s16x8 pb1 = *(const s16x8*)(pb + col * PSTRIDE + 32 + quad * 8);

            acc[qs][0] = __builtin_amdgcn_mfma_f32_16x16x32_bf16(vf00, pb0, acc[qs][0], 0, 0, 0);
            acc[qs][0] = __builtin_amdgcn_mfma_f32_16x16x32_bf16(vf01, pb1, acc[qs][0], 0, 0, 0);
            acc[qs][1] = __builtin_amdgcn_mfma_f32_16x16x32_bf16(vf10, pb0, acc[qs][1], 0, 0, 0);
            acc[qs][1] = __builtin_amdgcn_mfma_f32_16x16x32_bf16(vf11, pb1, acc[qs][1], 0, 0, 0);
        }
    }

    // partition partials to LDS (plain sums; no rescale needed with fixed M)
#pragma unroll
    for (int qs = 0; qs < 2; ++qs) {
        float r = rs[qs];
        r += __shfl_xor(r, 16, 64);
        r += __shfl_xor(r, 32, 64);
        if (quad == 0) sl[wv][qs * 16 + col] = r;
#pragma unroll
        for (int rr = 0; rr < 4; ++rr) {
            sO[wv][quad * 4 + rr][qs * 16 + col]      = acc[qs][0][rr];
            sO[wv][16 + quad * 4 + rr][qs * 16 + col] = acc[qs][1][rr];
        }
    }
    __syncthreads();

    // merge 4 key-partitions; thread -> (q = tid>>3, 4 consecutive hd)
    const int q = tid >> 3, hd0 = (tid & 7) * 4;
    float l = sl[0][q] + sl[1][q] + sl[2][q] + sl[3][q];
    float inv = 1.f / l;  // diagonal always allowed -> l > 0
    float o[4];
#pragma unroll
    for (int j = 0; j < 4; ++j) {
        int hd = hd0 + j;
        o[j] = (sO[0][hd][q] + sO[1][hd][q] + sO[2][hd][q] + sO[3][hd][q]) * inv;
    }
    uint2 ob;
    ob.x = pk_bf16(o[0], o[1]);
    ob.y = pk_bf16(o[2], o[3]);
    *(uint2*)(Om + (size_t)(q0 + q) * DMODEL + h * HDIM + hd0) = ob;
}

// ---------------------------------------------------------------------------
// bf16-in GEMM, compile-time K (fully unrolled K-loop).
template<int K, bool RELU, bool B16OUT>
__global__ __launch_bounds__(256) void gemm_t(const short* __restrict__ A,
                                              const short* __restrict__ W,
                                              const float* __restrict__ bias,
                                              float* __restrict__ Cf,
                                              short* __restrict__ Cb,
                                              int Ocols) {
    const int tid = threadIdx.x;
    const int wv = tid >> 6, lane = tid & 63;
    const int quad = lane >> 4, col = lane & 15;
    const int n0 = blockIdx.x * 64 + wv * 16;
    const int o0 = blockIdx.y * 64;
    f32x4 zero = {0.f, 0.f, 0.f, 0.f};
    f32x4 acc[4] = {zero, zero, zero, zero};
    const short* ap = A + (size_t)(n0 + col) * K + quad * 8;
    const short* wp = W + (size_t)(o0 + col) * K + quad * 8;
#pragma unroll
    for (int k0 = 0; k0 < K; k0 += 32) {
        s16x8 af = *(const s16x8*)(ap + k0);
#pragma unroll
        for (int c = 0; c < 4; ++c) {
            s16x8 bf = *(const s16x8*)(wp + (size_t)c * 16 * K + k0);
            acc[c] = __builtin_amdgcn_mfma_f32_16x16x32_bf16(af, bf, acc[c], 0, 0, 0);
        }
    }
#pragma unroll
    for (int c = 0; c < 4; ++c) {
        int o = o0 + c * 16 + col;
        float bvv = bias[o];
#pragma unroll
        for (int r = 0; r < 4; ++r) {
            int n = n0 + quad * 4 + r;
            float v = acc[c][r] + bvv;
            if (RELU) v = fmaxf(v, 0.f);
            if (B16OUT) Cb[(size_t)n * Ocols + o] = bf16r(v);
            else        Cf[(size_t)n * Ocols + o] = v;
        }
    }
}

// ---------------------------------------------------------------------------
// y = LN(a+b)*g + beta; writes f32 Y and optional bf16 Yb.
__global__ __launch_bounds__(256) void ln_kernel(const float* __restrict__ Xa,
                                                 const float* __restrict__ Xb,
                                                 const float* __restrict__ g,
                                                 const float* __restrict__ be,
                                                 float* __restrict__ Y,
                                                 short* __restrict__ Yb) {
    const int wv = threadIdx.x >> 6, lane = threadIdx.x & 63;
    const int row = blockIdx.x * 4 + wv;
    const float4 av = *(const float4*)(Xa + (size_t)row * DMODEL + lane * 4);
    const float4 bv = *(const float4*)(Xb + (size_t)row * DMODEL + lane * 4);
    float v0 = av.x + bv.x, v1 = av.y + bv.y, v2 = av.z + bv.z, v3 = av.w + bv.w;
    float s = v0 + v1 + v2 + v3;
#pragma unroll
    for (int m = 1; m < 64; m <<= 1) s += __shfl_xor(s, m, 64);
    float mean = s * (1.f / 256.f);
    float d0 = v0 - mean, d1 = v1 - mean, d2 = v2 - mean, d3 = v3 - mean;
    float q = d0 * d0 + d1 * d1 + d2 * d2 + d3 * d3;
#pragma unroll
    for (int m = 1; m < 64; m <<= 1) q += __shfl_xor(q, m, 64);
    float rstd = rsqrtf(q * (1.f / 256.f) + 1e-5f);
    const float4 gv  = *(const float4*)(g + lane * 4);
    const float4 bev = *(const float4*)(be + lane * 4);
    float4 y;
    y.x = d0 * rstd * gv.x + bev.x;
    y.y = d1 * rstd * gv.y + bev.y;
    y.z = d2 * rstd * gv.z + bev.z;
    y.w = d3 * rstd * gv.w + bev.w;
    *(float4*)(Y + (size_t)row * DMODEL + lane * 4) = y;
    if (Yb) {
        uint2 yb;
        yb.x = pk_bf16(y.x, y.y);
        yb.y = pk_bf16(y.z, y.w);
        *(uint2*)(Yb + (size_t)row * DMODEL + lane * 4) = yb;
    }
}

// ---------------------------------------------------------------------------
extern "C" void kernel_launch(void* const* d_in, const int* in_sizes, int n_in,
                              void* d_out, int out_size, void* d_ws, size_t ws_size,
                              hipStream_t stream) {
    const float* x   = (const float*)d_in[0];
    const int*   adj = (const int*)d_in[1];
    const float* Wq  = (const float*)d_in[2];
    const float* Wk  = (const float*)d_in[3];
    const float* Wv  = (const float*)d_in[4];
    const float* bq  = (const float*)d_in[5];
    const float* bk  = (const float*)d_in[6];
    const float* bv  = (const float*)d_in[7];
    const float* Wo  = (const float*)d_in[8];
    const float* bo  = (const float*)d_in[9];
    const float* g1  = (const float*)d_in[10];
    const float* be1 = (const float*)d_in[11];
    const float* W1  = (const float*)d_in[12];
    const float* b1  = (const float*)d_in[13];
    const float* W2  = (const float*)d_in[14];
    const float* b2  = (const float*)d_in[15];
    const float* g2  = (const float*)d_in[16];
    const float* be2 = (const float*)d_in[17];
    float* out = (float*)d_out;

    const size_t NM = (size_t)NROWS * DMODEL;
    char* p = (char*)d_ws;
    unsigned* mask = (unsigned*)p; p += (size_t)NROWS * 128 * 4;  // 2 MB
    short* Wb   = (short*)p;       p += (size_t)524288 * 2;       // 1 MB
    short* Qb   = (short*)p;       p += NM * 2;                   // 2 MB
    short* Kb   = (short*)p;       p += NM * 2;                   // 2 MB
    short* Vtb  = (short*)p;       p += NM * 2;                   // 2 MB
    short* Omb  = (short*)p;       p += NM * 2;                   // 2 MB
    float* hbuf = (float*)p;       p += NM * 4;                   // 4 MB
    float* y1   = (float*)p;       p += NM * 4;                   // 4 MB
    short* y1b  = (short*)p;       p += NM * 2;                   // 2 MB
    short* rbuf = (short*)p;       p += (size_t)NROWS * 512 * 2;  // 4 MB
    float* t2   = (float*)p;       p += NM * 4;                   // 4 MB

    pack_adj<<<dim3(NROWS * 64 / 4), dim3(256), 0, stream>>>(adj, mask);
    prep_w<<<dim3(256), dim3(256), 0, stream>>>(Wq, Wk, Wv, Wo, W1, W2, Wb);
    qkv_kernel<<<dim3(64, 4, 3), dim3(256), 0, stream>>>(x, Wb, bq, bk, bv, Qb, Kb, Vtb);
    attn_kernel<<<dim3(1024), dim3(256), 0, stream>>>(Qb, Kb, Vtb, mask, Omb);
    gemm_t<256, false, false><<<dim3(64, 4), dim3(256), 0, stream>>>(Omb, Wb + 196608, bo, hbuf, nullptr, 256);
    ln_kernel<<<dim3(1024), dim3(256), 0, stream>>>(x, hbuf, g1, be1, y1, y1b);
    gemm_t<256, true, true><<<dim3(64, 8), dim3(256), 0, stream>>>(y1b, Wb + 262144, b1, nullptr, rbuf, 512);
    gemm_t<512, false, false><<<dim3(64, 4), dim3(256), 0, stream>>>(rbuf, Wb + 393216, b2, t2, nullptr, 256);
    ln_kernel<<<dim3(1024), dim3(256), 0, stream>>>(y1, t2, g2, be2, out, nullptr);
}